// Round 2
// baseline (955.688 us; speedup 1.0000x reference)
//
#include <hip/hip_runtime.h>
#include <hip/hip_bf16.h>

// Problem constants
#define NH 4
#define DKV 64
#define DM 256
#define NB 8
#define NL 2048
#define LN_EPS 1e-5f

typedef __hip_bfloat16 bf16;
typedef __attribute__((ext_vector_type(8))) short short8;
typedef __attribute__((ext_vector_type(4))) float f32x4;

#define MFMA(a, b, c) __builtin_amdgcn_mfma_f32_16x16x32_bf16((a), (b), (c), 0, 0, 0)

__device__ __forceinline__ short f2bf(float f) {
  __hip_bfloat16 h = __float2bfloat16(f);
  return *reinterpret_cast<short*>(&h);
}

// ---------------------------------------------------------------------------
// Kernel 1: transpose weights to [N][K] bf16 (so MFMA B-fragments are 8
// contiguous bf16 per lane), and precompute additive mask (-1e30 where masked).
// ---------------------------------------------------------------------------
__global__ __launch_bounds__(256) void prep_kernel(
    const float* __restrict__ wq, const float* __restrict__ wk,
    const float* __restrict__ wv, const float* __restrict__ wf,
    const int* __restrict__ mask, bf16* __restrict__ wqT,
    bf16* __restrict__ wkT, bf16* __restrict__ wvT, bf16* __restrict__ wfT,
    float* __restrict__ maskadd) {
  int idx = blockIdx.x * 256 + threadIdx.x;
  if (idx < 4 * 65536) {
    int w = idx >> 16;
    int rem = idx & 65535;
    int k = rem >> 8, n = rem & 255;
    const float* src = (w == 0) ? wq : (w == 1) ? wk : (w == 2) ? wv : wf;
    bf16* dst = (w == 0) ? wqT : (w == 1) ? wkT : (w == 2) ? wvT : wfT;
    dst[n * 256 + k] = __float2bfloat16(src[k * 256 + n]);
  } else {
    int i = idx - 4 * 65536;
    if (i < NB * NL) maskadd[i] = mask[i] ? -1e30f : 0.0f;
  }
}

// ---------------------------------------------------------------------------
// Kernel 2: projection GEMM  Y = X @ W^T(bf16) + bias, X f32 [16384,256].
// MODE 0: write bf16 [row][col] (qh / kh). scale folds 1/sqrt(dk) for qh.
// MODE 1: write V transposed: vhT[b][h][dv][kpos]  (for PV B-fragments).
// Block: 256 thr (4 waves). Wave = 16 rows x 64 cols. Grid (256, 4).
// ---------------------------------------------------------------------------
template <int MODE>
__global__ __launch_bounds__(256) void proj_kernel(
    const float* __restrict__ x, const bf16* __restrict__ wT,
    const float* __restrict__ bias, float scale, bf16* __restrict__ out) {
  int lane = threadIdx.x & 63;
  int w = threadIdx.x >> 6;
  int col = lane & 15, g = lane >> 4;
  int rbase = blockIdx.x * 64 + w * 16;
  int cbase = blockIdx.y * 64;

  f32x4 acc[4] = {{0.f, 0.f, 0.f, 0.f},
                  {0.f, 0.f, 0.f, 0.f},
                  {0.f, 0.f, 0.f, 0.f},
                  {0.f, 0.f, 0.f, 0.f}};
  const float* ap = x + (size_t)(rbase + col) * DM;

#pragma unroll
  for (int ks = 0; ks < 8; ++ks) {
    int koff = ks * 32 + g * 8;
    f32x4 x0 = *(const f32x4*)(ap + koff);
    f32x4 x1 = *(const f32x4*)(ap + koff + 4);
    short8 a;
    a[0] = f2bf(x0[0]); a[1] = f2bf(x0[1]); a[2] = f2bf(x0[2]); a[3] = f2bf(x0[3]);
    a[4] = f2bf(x1[0]); a[5] = f2bf(x1[1]); a[6] = f2bf(x1[2]); a[7] = f2bf(x1[3]);
#pragma unroll
    for (int ct = 0; ct < 4; ++ct) {
      short8 b = *(const short8*)(wT + (size_t)(cbase + ct * 16 + col) * DM + koff);
      acc[ct] = MFMA(a, b, acc[ct]);
    }
  }

#pragma unroll
  for (int ct = 0; ct < 4; ++ct) {
    int cg = cbase + ct * 16 + col;
    float bv = bias[cg];
#pragma unroll
    for (int r = 0; r < 4; ++r) {
      int rg = rbase + g * 4 + r;
      float val = (acc[ct][r] + bv) * scale;
      if (MODE == 0) {
        out[(size_t)rg * DM + cg] = __float2bfloat16(val);
      } else {
        int bI = rg >> 11, kpos = rg & (NL - 1);
        int hh = cg >> 6, dv = cg & 63;
        out[((size_t)((bI * NH + hh) * 64 + dv)) * NL + kpos] = __float2bfloat16(val);
      }
    }
  }
}

// ---------------------------------------------------------------------------
// Kernel 3: attention. One block = (b, h, 64 q-rows); 4 waves x 16 rows each.
// Pass A: stream K-tiles (64 cols), MFMA scores, online (m, l) — no storage.
// Pass B: recompute scores, write normalized P f32 to d_out (nontemporal:
//         pure streaming output, keep it out of L2/LLC so kh/vhT stay
//         resident), P->bf16 via per-wave LDS transpose, PV MFMA.
// ---------------------------------------------------------------------------
__global__ __launch_bounds__(256) void attn_kernel(
    const bf16* __restrict__ qh, const bf16* __restrict__ kh,
    const bf16* __restrict__ vhT, const float* __restrict__ maskadd,
    float* __restrict__ attn_f, float* __restrict__ aout) {
  __shared__ bf16 ldsP[4][16][72];  // per-wave 16x64 P tile, padded stride

  int lane = threadIdx.x & 63;
  int w = threadIdx.x >> 6;
  int col = lane & 15, g = lane >> 4;

  int bid = blockIdx.x;
  int qt = bid & 31;           // q tile
  int bh = bid >> 5;           // == h*8 + b  (== attn output row-block index)
  int b = bh & 7, h = bh >> 3;
  int qbase = qt * 64 + w * 16;

  // Q fragments (scale already folded into qh)
  const bf16* qrow = qh + (size_t)(b * NL + qbase + col) * DM + h * 64;
  short8 aq0 = *(const short8*)(qrow + g * 8);
  short8 aq1 = *(const short8*)(qrow + 32 + g * 8);

  const bf16* khb = kh + (size_t)(b * NL) * DM + h * 64;
  const bf16* vtb = vhT + (size_t)((b * NH + h) * 64) * NL;
  const float* madd_b = maskadd + b * NL;

  float m[4], l[4];
#pragma unroll
  for (int r = 0; r < 4; ++r) { m[r] = -1e30f; l[r] = 0.f; }

  // ---- Pass A: exact row max + denom ----
  for (int kt = 0; kt < NL; kt += 64) {
    float s[4][4];
#pragma unroll
    for (int ct = 0; ct < 4; ++ct) {
      int kk = kt + ct * 16 + col;
      const bf16* kpr = khb + (size_t)kk * DM;
      short8 b0 = *(const short8*)(kpr + g * 8);
      short8 b1 = *(const short8*)(kpr + 32 + g * 8);
      f32x4 c = {0.f, 0.f, 0.f, 0.f};
      c = MFMA(aq0, b0, c);
      c = MFMA(aq1, b1, c);
      float ma = madd_b[kk];
#pragma unroll
      for (int r = 0; r < 4; ++r) s[ct][r] = c[r] + ma;
    }
    float mx[4], mn[4], ps[4];
#pragma unroll
    for (int r = 0; r < 4; ++r)
      mx[r] = fmaxf(fmaxf(s[0][r], s[1][r]), fmaxf(s[2][r], s[3][r]));
#pragma unroll
    for (int st = 1; st <= 8; st <<= 1)
#pragma unroll
      for (int r = 0; r < 4; ++r) mx[r] = fmaxf(mx[r], __shfl_xor(mx[r], st));
#pragma unroll
    for (int r = 0; r < 4; ++r) {
      mn[r] = fmaxf(m[r], mx[r]);
      ps[r] = __expf(s[0][r] - mn[r]) + __expf(s[1][r] - mn[r]) +
              __expf(s[2][r] - mn[r]) + __expf(s[3][r] - mn[r]);
    }
#pragma unroll
    for (int st = 1; st <= 8; st <<= 1)
#pragma unroll
      for (int r = 0; r < 4; ++r) ps[r] += __shfl_xor(ps[r], st);
#pragma unroll
    for (int r = 0; r < 4; ++r) {
      l[r] = l[r] * __expf(m[r] - mn[r]) + ps[r];
      m[r] = mn[r];
    }
  }
  float inv_l[4];
#pragma unroll
  for (int r = 0; r < 4; ++r) inv_l[r] = 1.0f / l[r];

  // ---- Pass B: normalized P out + PV ----
  f32x4 accO[4] = {{0.f, 0.f, 0.f, 0.f},
                   {0.f, 0.f, 0.f, 0.f},
                   {0.f, 0.f, 0.f, 0.f},
                   {0.f, 0.f, 0.f, 0.f}};
  size_t attn_row0 = (size_t)bh * NL * NL;

  for (int kt = 0; kt < NL; kt += 64) {
#pragma unroll
    for (int ct = 0; ct < 4; ++ct) {
      int kk = kt + ct * 16 + col;
      const bf16* kpr = khb + (size_t)kk * DM;
      short8 b0 = *(const short8*)(kpr + g * 8);
      short8 b1 = *(const short8*)(kpr + 32 + g * 8);
      f32x4 c = {0.f, 0.f, 0.f, 0.f};
      c = MFMA(aq0, b0, c);
      c = MFMA(aq1, b1, c);
      float ma = madd_b[kk];
#pragma unroll
      for (int r = 0; r < 4; ++r) {
        float p = __expf(c[r] + ma - m[r]) * inv_l[r];
        __builtin_nontemporal_store(
            p, &attn_f[attn_row0 + (size_t)(qbase + g * 4 + r) * NL + kk]);
        ldsP[w][g * 4 + r][ct * 16 + col] = __float2bfloat16(p);
      }
    }
    // wave-local LDS transpose: C-layout -> A-layout (compiler inserts lgkmcnt)
    short8 ap0 = *(const short8*)(&ldsP[w][col][g * 8]);
    short8 ap1 = *(const short8*)(&ldsP[w][col][32 + g * 8]);
#pragma unroll
    for (int dvt = 0; dvt < 4; ++dvt) {
      const bf16* vp = vtb + (size_t)(dvt * 16 + col) * NL + kt;
      short8 v0 = *(const short8*)(vp + g * 8);
      short8 v1 = *(const short8*)(vp + 32 + g * 8);
      accO[dvt] = MFMA(ap0, v0, accO[dvt]);
      accO[dvt] = MFMA(ap1, v1, accO[dvt]);
    }
  }

#pragma unroll
  for (int dvt = 0; dvt < 4; ++dvt)
#pragma unroll
    for (int r = 0; r < 4; ++r)
      aout[(size_t)(b * NL + qbase + g * 4 + r) * DM + h * 64 + dvt * 16 + col] =
          accO[dvt][r];
}

// ---------------------------------------------------------------------------
// Kernel 4: out = LN(aout @ wf + bf + residual) — wave = 16 rows x all 256 cols
// so the LayerNorm reduction stays in-wave (shuffle over 16 lanes).
// ---------------------------------------------------------------------------
__global__ __launch_bounds__(256) void final_kernel(
    const float* __restrict__ aout, const bf16* __restrict__ wfT,
    const float* __restrict__ bf_, const float* __restrict__ resid,
    const float* __restrict__ gamma, const float* __restrict__ beta,
    float* __restrict__ out) {
  int lane = threadIdx.x & 63;
  int w = threadIdx.x >> 6;
  int col = lane & 15, g = lane >> 4;
  int rbase = blockIdx.x * 64 + w * 16;

  f32x4 acc[16];
#pragma unroll
  for (int ct = 0; ct < 16; ++ct) acc[ct] = (f32x4){0.f, 0.f, 0.f, 0.f};

  const float* ap = aout + (size_t)(rbase + col) * DM;
#pragma unroll
  for (int ks = 0; ks < 8; ++ks) {
    int koff = ks * 32 + g * 8;
    f32x4 x0 = *(const f32x4*)(ap + koff);
    f32x4 x1 = *(const f32x4*)(ap + koff + 4);
    short8 a;
    a[0] = f2bf(x0[0]); a[1] = f2bf(x0[1]); a[2] = f2bf(x0[2]); a[3] = f2bf(x0[3]);
    a[4] = f2bf(x1[0]); a[5] = f2bf(x1[1]); a[6] = f2bf(x1[2]); a[7] = f2bf(x1[3]);
#pragma unroll
    for (int ct = 0; ct < 16; ++ct) {
      short8 b = *(const short8*)(wfT + (size_t)(ct * 16 + col) * DM + koff);
      acc[ct] = MFMA(a, b, acc[ct]);
    }
  }

  float sum[4] = {0.f, 0.f, 0.f, 0.f}, sq[4] = {0.f, 0.f, 0.f, 0.f};
#pragma unroll
  for (int ct = 0; ct < 16; ++ct) {
    int cg = ct * 16 + col;
    float bv = bf_[cg];
#pragma unroll
    for (int r = 0; r < 4; ++r) {
      int rg = rbase + g * 4 + r;
      float xv = acc[ct][r] + bv + resid[(size_t)rg * DM + cg];
      acc[ct][r] = xv;
      sum[r] += xv;
      sq[r] += xv * xv;
    }
  }
#pragma unroll
  for (int st = 1; st <= 8; st <<= 1)
#pragma unroll
    for (int r = 0; r < 4; ++r) {
      sum[r] += __shfl_xor(sum[r], st);
      sq[r] += __shfl_xor(sq[r], st);
    }
  float mu[4], rstd[4];
#pragma unroll
  for (int r = 0; r < 4; ++r) {
    mu[r] = sum[r] * (1.0f / 256.0f);
    float var = sq[r] * (1.0f / 256.0f) - mu[r] * mu[r];
    rstd[r] = rsqrtf(var + LN_EPS);
  }
#pragma unroll
  for (int ct = 0; ct < 16; ++ct) {
    int cg = ct * 16 + col;
    float gm = gamma[cg], bt = beta[cg];
#pragma unroll
    for (int r = 0; r < 4; ++r) {
      int rg = rbase + g * 4 + r;
      out[(size_t)rg * DM + cg] = gm * (acc[ct][r] - mu[r]) * rstd[r] + bt;
    }
  }
}

// ---------------------------------------------------------------------------
extern "C" void kernel_launch(void* const* d_in, const int* in_sizes, int n_in,
                              void* d_out, int out_size, void* d_ws,
                              size_t ws_size, hipStream_t stream) {
  const float* q     = (const float*)d_in[0];
  const float* k     = (const float*)d_in[1];
  const float* v     = (const float*)d_in[2];
  const int*   mask  = (const int*)d_in[3];  // NOTE: assuming int32 bool
  const float* wq    = (const float*)d_in[4];
  const float* bq    = (const float*)d_in[5];
  const float* wk    = (const float*)d_in[6];
  const float* bk    = (const float*)d_in[7];
  const float* wv    = (const float*)d_in[8];
  const float* bv    = (const float*)d_in[9];
  const float* wf    = (const float*)d_in[10];
  const float* bf_   = (const float*)d_in[11];
  const float* gamma = (const float*)d_in[12];
  const float* beta  = (const float*)d_in[13];

  char* ws = (char*)d_ws;
  bf16* wqT = (bf16*)(ws);
  bf16* wkT = (bf16*)(ws + (1 << 17));
  bf16* wvT = (bf16*)(ws + 2 * (1 << 17));
  bf16* wfT = (bf16*)(ws + 3 * (1 << 17));
  float* maskadd = (float*)(ws + 4 * (1 << 17));
  bf16* qh = (bf16*)(ws + 4 * (1 << 17) + (1 << 16));
  bf16* kh = qh + (size_t)16384 * 256;
  bf16* vhT = kh + (size_t)16384 * 256;
  float* aout = (float*)(vhT + (size_t)16384 * 256);

  float* out_f = (float*)d_out;
  float* attn_f = out_f + (size_t)16384 * 256;

  prep_kernel<<<1088, 256, 0, stream>>>(wq, wk, wv, wf, mask, wqT, wkT, wvT,
                                        wfT, maskadd);
  proj_kernel<0><<<dim3(256, 4), 256, 0, stream>>>(q, wqT, bq, 0.125f, qh);
  proj_kernel<0><<<dim3(256, 4), 256, 0, stream>>>(k, wkT, bk, 1.0f, kh);
  proj_kernel<1><<<dim3(256, 4), 256, 0, stream>>>(v, wvT, bv, 1.0f, vhT);
  attn_kernel<<<1024, 256, 0, stream>>>(qh, kh, vhT, maskadd, attn_f, aout);
  final_kernel<<<256, 256, 0, stream>>>(aout, wfT, bf_, q, gamma, beta, out_f);
}